// Round 12
// baseline (282.214 us; speedup 1.0000x reference)
//
#include <hip/hip_runtime.h>

// PSAMask collect: out[(nh*97+nw)*9409 + h*97 + w] = x[(nh-h+48)*97 + (nw-w+48)][h][w]
// (valid window, else 0). Pure shear permutation -> memory-bound.
//
// R12 = R8 (h-pair blocks, XCD-pinned, 2 blocks/CU, full-drain sync) with the
// SHEAR APPLIED AT STAGE TIME: DMA per-lane source is free, so LDS holds the
// slab in OUTPUT order: lds[q*196 + e] = x[(a0-p)*97 + (q - w + 48)][h0+p][w]
// (e = w + 97p, run stride 196 floats -> 16B-aligned float4 cells; invalid
// cells DMA from a .rodata zero array). Write phase is then branchless:
// ds_read_b128 (linear, conflict-free) + global_store_dwordx4 (4B-aligned
// multi-dword global ops are legal; compiler may split -> degrades to R8).
// Single variable vs R8: store width 4B -> 16B/lane.

#define HW    97
#define PLANE 9409      // 97*97
#define HALF  48
#define NT    512
#define RSTR  196       // LDS floats per channel run (194 data + 2 pad), 784B = 49*16
#define NLDS  19456     // 38*512 : DMA-covered LDS floats (>= 97*196 = 19012)
#define DITER 38        // NLDS / NT
#define NV4   4656      // 97*48 float4 stores per slab
#define V4IT  10        // ceil(NV4/NT)

typedef const __attribute__((address_space(1))) void* gptr_t;
typedef __attribute__((address_space(3))) void* lptr_t;
using f4v = __attribute__((ext_vector_type(4))) float;
typedef f4v f4v_u __attribute__((aligned(4)));   // 4B-aligned 16B store

__device__ const float g_zero[16] = {};          // .rodata zeros (DMA source)

__global__ __launch_bounds__(NT)
void psamask_shear(const float* __restrict__ x, float* __restrict__ out) {
    // ---- XCD-pinned decode (R8): digit xcd -> nh = 8g + xcd; 49 chunks/nh
    const unsigned l   = blockIdx.x;
    const unsigned xcd = l & 7u;
    const unsigned m   = l >> 3;         // 0..636
    const unsigned g   = m / 49u;
    const unsigned cc  = m - g * 49u;    // 0..48
    const int nh = (int)(g * 8u + xcd);
    if (nh > 96) return;                 // padded blocks

    int h0 = 2 * (int)cc; if (h0 > 95) h0 = 95;   // c=48 -> pair {95,96}; row 95
    const unsigned tid = threadIdx.x;             // double-written (identical vals)

    __shared__ float lds[NLDS];          // 77,824 B -> 2 blocks/CU

    const int a0  = nh - h0 + HALF;
    const unsigned av0 = ((unsigned)a0       < HW) ? 1u : 0u;
    const unsigned av1 = ((unsigned)(a0 - 1) < HW) ? 1u : 0u;

    // wave-uniform plane bases (clamped; invalid planes never dereferenced)
    const unsigned ac0 = (a0 < 0) ? 0u : ((a0 > 96) ? 96u : (unsigned)a0);
    const int a1 = a0 - 1;
    const unsigned ac1 = (a1 < 0) ? 0u : ((a1 > 96) ? 96u : (unsigned)a1);
    const float* __restrict__ xb0 =
        x + (size_t)(ac0 * HW) * PLANE + (unsigned)h0 * HW;
    const float* __restrict__ xb1 =
        x + (size_t)(ac1 * HW) * PLANE + (unsigned)(h0 + 1) * HW;
    const float* zp = &g_zero[tid & 15u];

    // ---- stage: lds[q*196 + e] = shear(q,e); invalid -> zero word.  DMA width 4.
    {
        unsigned q = tid / RSTR;                   // 0..2 (compiler magic-div)
        unsigned e = tid - q * RSTR;
        #pragma unroll
        for (int k = 0; k < DITER; ++k) {
            unsigned pad = (e >= 194u) | (q >= 97u);
            unsigned p   = (e >= HW && e < 194u) ? 1u : 0u;
            unsigned w   = e - p * HW;             // valid only when !pad
            int b = (int)q - (int)w + HALF;        // nw - w + 48
            unsigned vb = ((unsigned)b < HW) ? 1u : 0u;
            unsigned pv = p ? av1 : av0;
            bool use = (vb & pv & (1u - pad)) != 0u;
            const float* base = p ? xb1 : xb0;
            const float* src  = use ? (base + (unsigned)b * PLANE + w) : zp;
            unsigned d0 = (unsigned)k * NT + (tid & ~63u);   // wave-uniform dest
            __builtin_amdgcn_global_load_lds((gptr_t)src, (lptr_t)&lds[d0], 4, 0, 0);
            // d += 512 = 2*196 + 120
            e += 120u; q += 2u;
            if (e >= RSTR) { e -= RSTR; q += 1u; }
        }
    }
    asm volatile("s_waitcnt vmcnt(0)" ::: "memory");
    __syncthreads();

    // ---- write: branchless float4 stream, 97 runs x (48 x4 + 2 tail dwords)
    float* __restrict__ outp =
        out + (size_t)((unsigned)nh * HW) * PLANE + (unsigned)h0 * HW;
    {
        unsigned q = tid / 48u;                    // compiler magic-div
        unsigned i = tid - q * 48u;
        unsigned loff = q * RSTR + 4u * i;         // 16B-aligned (196*4=49*16)
        unsigned goff = q * PLANE + 4u * i;
        #pragma unroll
        for (int k = 0; k < V4IT; ++k) {
            unsigned v = tid + (unsigned)k * NT;
            if (v < NV4) {
                f4v val = *(const f4v*)&lds[loff];        // ds_read_b128
                *(f4v_u*)(outp + goff) = val;             // dwordx4 (align 4)
            }
            // v += 512 = 10*48 + 32
            i += 32u; loff += 10u * RSTR + 128u; goff += 10u * PLANE + 128u;
            if (i >= 48u) { i -= 48u; loff += RSTR - 192u; goff += PLANE - 192u; }
            q += 10u;  // (kept for clarity; not otherwise used)
        }
    }
    if (tid < HW) {                                // per-run 2-float tail (e=192,193)
        unsigned lo = tid * RSTR + 192u;
        unsigned go = tid * PLANE + 192u;
        outp[go]      = lds[lo];
        outp[go + 1u] = lds[lo + 1u];
    }
}

extern "C" void kernel_launch(void* const* d_in, const int* in_sizes, int n_in,
                              void* d_out, int out_size, void* d_ws, size_t ws_size,
                              hipStream_t stream) {
    const float* x = (const float*)d_in[0];
    float* out = (float*)d_out;
    // 8 XCD digits x 637 (= 13*49) slots; nh>96 blocks early-exit (~7% pad)
    psamask_shear<<<dim3(5096), NT, 0, stream>>>(x, out);
}